// Round 4
// baseline (192.714 us; speedup 1.0000x reference)
//
#include <hip/hip_runtime.h>
#include <math.h>

// CellList dense masked-distance map, N=6144, no PBC.
// out[i*N+j] = |r_i - r_j| if (i>j && species_i!=-1 && species_j!=-1 &&
//                              dist<=cutoff && sq>0) else 0.
//
// HBM-write-bound: 151 MB output, floor ~23 us @ 6.5 TB/s. R4 = R3 with the
// nontemporal-store type fixed (clang ext_vector, not HIP float4):
//  - 3072 blocks (12/CU); each block = one 2048-col strip x 6 consecutive
//    rows. j-side coords/species loaded ONCE per thread, reused across the
//    6 rows (6x less L2 read traffic, 12 stores/wave instead of 2).
//  - upper-triangle / dummy rows: pure zero stores, no loads/math.
//  - mask via sq <= T (T = largest f32 with sqrt_rn(T) <= cutoff) -- bit-
//    exact vs reference (R2 absmax = 0.0), no per-element IEEE sqrt.
//  - dist via raw v_sqrt_f32 (1 ulp; threshold 0.1).
//  - sq in numpy's ((x*x + y*y) + z*z) order, no FMA contraction.
//  - nontemporal stores: output is write-once, bypass L2 allocation.

typedef float v4f __attribute__((ext_vector_type(4)));

constexpr int N      = 6144;
constexpr int CPT    = 8;            // columns per thread
constexpr int BLOCK  = 256;
constexpr int CPB    = BLOCK * CPT;  // 2048 columns per block
constexpr int NSTRIP = N / CPB;      // 3 column strips
constexpr int RPB    = 6;            // rows per block
constexpr int NROWG  = N / RPB;      // 1024 row groups

__global__ __launch_bounds__(BLOCK) void cell_list_kernel(
    const float* __restrict__ coords,   // [N][3] f32
    const int*   __restrict__ species,  // [N] i32
    const int*   __restrict__ cutoff_p, // [1] i32
    float*       __restrict__ out)      // [N][N] f32
{
    const int bx    = blockIdx.x;
    const int strip = bx % NSTRIP;
    const int i0    = (bx / NSTRIP) * RPB;
    const int base  = strip * CPB;
    const int j0    = base + (int)threadIdx.x * CPT;

    // T = largest f32 x with sqrt_rn(x) <= c: sqrt_rn(x) <= c iff
    // sqrt_exact(x) < c + 0.5*ulp(c) (tie impossible: midpoint^2 not f32-
    // representable). Exact in double, rounded down. Scalar, once.
    const float  c  = (float)cutoff_p[0];
    const float  cn = __int_as_float(__float_as_int(c) + 1);
    const double md = (double)c + 0.5 * ((double)cn - (double)c);
    const double Td = md * md;
    float T = (float)Td;
    if ((double)T > Td) T = __int_as_float(__float_as_int(T) - 1);

    // Load j-side data once per thread iff any row in this block computes.
    float f[24];
    int   sj[8];
    if (i0 + RPB - 1 > base) {
        const float4* cj = reinterpret_cast<const float4*>(coords + 3 * (size_t)j0);
#pragma unroll
        for (int q = 0; q < 6; ++q) {
            const float4 v = cj[q];
            f[4 * q + 0] = v.x; f[4 * q + 1] = v.y;
            f[4 * q + 2] = v.z; f[4 * q + 3] = v.w;
        }
        const int4 sa = *reinterpret_cast<const int4*>(species + j0);
        const int4 sb = *reinterpret_cast<const int4*>(species + j0 + 4);
        sj[0] = sa.x; sj[1] = sa.y; sj[2] = sa.z; sj[3] = sa.w;
        sj[4] = sb.x; sj[5] = sb.y; sj[6] = sb.z; sj[7] = sb.w;
    }

    const v4f zero4 = {0.f, 0.f, 0.f, 0.f};

    for (int rr = 0; rr < RPB; ++rr) {
        const int i = i0 + rr;
        v4f* ov = reinterpret_cast<v4f*>(out + (size_t)i * N + j0);
        const int si = species[i];  // block-uniform -> scalar load

        if (i <= base || si == -1) {  // whole strip j >= i, or dummy row
            __builtin_nontemporal_store(zero4, ov + 0);
            __builtin_nontemporal_store(zero4, ov + 1);
            continue;
        }

        const float xi = coords[3 * i + 0];
        const float yi = coords[3 * i + 1];
        const float zi = coords[3 * i + 2];

        float r[8];
#pragma unroll
        for (int k = 0; k < 8; ++k) {
            // Exact numpy order: (dx*dx + dy*dy) + dz*dz, no FMA.
            const float dx = __fsub_rn(xi, f[3 * k + 0]);
            const float dy = __fsub_rn(yi, f[3 * k + 1]);
            const float dz = __fsub_rn(zi, f[3 * k + 2]);
            const float sq = __fadd_rn(
                __fadd_rn(__fmul_rn(dx, dx), __fmul_rn(dy, dy)),
                __fmul_rn(dz, dz));
            const bool m = (sq <= T) && (sj[k] != -1) && (j0 + k < i);
            r[k] = m ? __builtin_amdgcn_sqrtf(sq) : 0.0f;
        }
        const v4f lo = {r[0], r[1], r[2], r[3]};
        const v4f hi = {r[4], r[5], r[6], r[7]};
        __builtin_nontemporal_store(lo, ov + 0);
        __builtin_nontemporal_store(hi, ov + 1);
    }
}

extern "C" void kernel_launch(void* const* d_in, const int* in_sizes, int n_in,
                              void* d_out, int out_size, void* d_ws, size_t ws_size,
                              hipStream_t stream) {
    // setup_inputs() order: species (i32 [1,N]), coordinates (f32 [1,N,3]),
    // cutoff (python int -> i32 [1]).
    const int*   species = (const int*)d_in[0];
    const float* coords  = (const float*)d_in[1];
    const int*   cutoff  = (const int*)d_in[2];
    float*       out     = (float*)d_out;

    dim3 block(BLOCK);
    dim3 grid(NSTRIP * NROWG);  // 3072 blocks = 12/CU
    hipLaunchKernelGGL(cell_list_kernel, grid, block, 0, stream,
                       coords, species, cutoff, out);
}

// Round 5
// 157.818 us; speedup vs baseline: 1.2211x; 1.2211x over previous
//
#include <hip/hip_runtime.h>
#include <math.h>

// CellList dense masked-distance map, N=6144, no PBC.
// out[i*N+j] = |r_i - r_j| if (i>j && species_i!=-1 && species_j!=-1 &&
//                              dist<=cutoff && sq>0) else 0.
//
// R5 = R4 row-batched structure, but PLAIN cached stores. R4's nontemporal
// stores regressed 162->193 us: the 151 MB output fits in the 256 MiB L3,
// so cached stores are absorbed/written-back lazily while nt stores force
// the full HBM write onto the kernel's critical path.
//  - 3072 blocks (12/CU); each block = one 2048-col strip x 6 consecutive
//    rows. j-side coords/species loaded ONCE per thread, reused across the
//    6 rows (6x less L2 read traffic, 12 stores/wave instead of 2).
//  - upper-triangle / dummy rows: pure zero stores, no loads/math.
//  - mask via sq <= T (T = largest f32 with sqrt_rn(T) <= cutoff) -- bit-
//    exact vs reference (absmax 0.0 in R2/R4), no per-element IEEE sqrt.
//  - dist via raw v_sqrt_f32 (1 ulp; threshold 0.1).
//  - sq in numpy's ((x*x + y*y) + z*z) order, no FMA contraction.

constexpr int N      = 6144;
constexpr int CPT    = 8;            // columns per thread
constexpr int BLOCK  = 256;
constexpr int CPB    = BLOCK * CPT;  // 2048 columns per block
constexpr int NSTRIP = N / CPB;      // 3 column strips
constexpr int RPB    = 6;            // rows per block
constexpr int NROWG  = N / RPB;      // 1024 row groups

__global__ __launch_bounds__(BLOCK) void cell_list_kernel(
    const float* __restrict__ coords,   // [N][3] f32
    const int*   __restrict__ species,  // [N] i32
    const int*   __restrict__ cutoff_p, // [1] i32
    float*       __restrict__ out)      // [N][N] f32
{
    const int bx    = blockIdx.x;
    const int strip = bx % NSTRIP;
    const int i0    = (bx / NSTRIP) * RPB;
    const int base  = strip * CPB;
    const int j0    = base + (int)threadIdx.x * CPT;

    // T = largest f32 x with sqrt_rn(x) <= c: sqrt_rn(x) <= c iff
    // sqrt_exact(x) < c + 0.5*ulp(c) (tie impossible: midpoint^2 not f32-
    // representable). Exact in double, rounded down. Scalar, once.
    const float  c  = (float)cutoff_p[0];
    const float  cn = __int_as_float(__float_as_int(c) + 1);
    const double md = (double)c + 0.5 * ((double)cn - (double)c);
    const double Td = md * md;
    float T = (float)Td;
    if ((double)T > Td) T = __int_as_float(__float_as_int(T) - 1);

    // Load j-side data once per thread iff any row in this block computes.
    float f[24];
    int   sj[8];
    if (i0 + RPB - 1 > base) {
        const float4* cj = reinterpret_cast<const float4*>(coords + 3 * (size_t)j0);
#pragma unroll
        for (int q = 0; q < 6; ++q) {
            const float4 v = cj[q];
            f[4 * q + 0] = v.x; f[4 * q + 1] = v.y;
            f[4 * q + 2] = v.z; f[4 * q + 3] = v.w;
        }
        const int4 sa = *reinterpret_cast<const int4*>(species + j0);
        const int4 sb = *reinterpret_cast<const int4*>(species + j0 + 4);
        sj[0] = sa.x; sj[1] = sa.y; sj[2] = sa.z; sj[3] = sa.w;
        sj[4] = sb.x; sj[5] = sb.y; sj[6] = sb.z; sj[7] = sb.w;
    }

    const float4 zero4 = make_float4(0.f, 0.f, 0.f, 0.f);

    for (int rr = 0; rr < RPB; ++rr) {
        const int i = i0 + rr;
        float4* ov = reinterpret_cast<float4*>(out + (size_t)i * N + j0);
        const int si = species[i];  // block-uniform -> scalar load

        if (i <= base || si == -1) {  // whole strip j >= i, or dummy row
            ov[0] = zero4;
            ov[1] = zero4;
            continue;
        }

        const float xi = coords[3 * i + 0];
        const float yi = coords[3 * i + 1];
        const float zi = coords[3 * i + 2];

        float r[8];
#pragma unroll
        for (int k = 0; k < 8; ++k) {
            // Exact numpy order: (dx*dx + dy*dy) + dz*dz, no FMA.
            const float dx = __fsub_rn(xi, f[3 * k + 0]);
            const float dy = __fsub_rn(yi, f[3 * k + 1]);
            const float dz = __fsub_rn(zi, f[3 * k + 2]);
            const float sq = __fadd_rn(
                __fadd_rn(__fmul_rn(dx, dx), __fmul_rn(dy, dy)),
                __fmul_rn(dz, dz));
            const bool m = (sq <= T) && (sj[k] != -1) && (j0 + k < i);
            r[k] = m ? __builtin_amdgcn_sqrtf(sq) : 0.0f;
        }
        ov[0] = make_float4(r[0], r[1], r[2], r[3]);
        ov[1] = make_float4(r[4], r[5], r[6], r[7]);
    }
}

extern "C" void kernel_launch(void* const* d_in, const int* in_sizes, int n_in,
                              void* d_out, int out_size, void* d_ws, size_t ws_size,
                              hipStream_t stream) {
    // setup_inputs() order: species (i32 [1,N]), coordinates (f32 [1,N,3]),
    // cutoff (python int -> i32 [1]).
    const int*   species = (const int*)d_in[0];
    const float* coords  = (const float*)d_in[1];
    const int*   cutoff  = (const int*)d_in[2];
    float*       out     = (float*)d_out;

    dim3 block(BLOCK);
    dim3 grid(NSTRIP * NROWG);  // 3072 blocks = 12/CU
    hipLaunchKernelGGL(cell_list_kernel, grid, block, 0, stream,
                       coords, species, cutoff, out);
}